// Round 4
// baseline (1556.210 us; speedup 1.0000x reference)
//
#include <hip/hip_runtime.h>

// LSTM forward: B=65536, T=20, I=36, H=30. Gate order i,f,g,o.
// Inputs (fp32): x[B,T,I], W_ih[4H,I], W_hh[4H,H], b_ih[4H], b_hh[4H]
// Output (fp32, concat): out[B,T,H], h_n[1,B,H], c_n[1,B,H]
// Evidence for dtypes (R1-R3): inputs-as-bf16 => NaN (they're fp32);
// bf16-packed output => err 1.705 == fp32-reinterpret garbage (it's fp32).

constexpr int BB = 65536;
constexpr int TT = 20;
constexpr int II = 36;
constexpr int HH = 30;

__device__ __forceinline__ float fast_sigmoid(float v) {
    float e = __expf(-v);                      // v_exp_f32
    return __builtin_amdgcn_rcpf(1.f + e);     // v_rcp_f32
}
__device__ __forceinline__ float fast_tanh(float v) {
    // 1 - 2/(exp(2v)+1): saturates to +/-1, no inf/inf NaN
    float e = __expf(2.f * v);
    return 1.f - 2.f * __builtin_amdgcn_rcpf(e + 1.f);
}

__global__ __launch_bounds__(256) void lstm_fwd(
    const float* __restrict__ x,
    const float* __restrict__ Wih,   // [4H][II] row-major, gate rows i,f,g,o
    const float* __restrict__ Whh,   // [4H][HH]
    const float* __restrict__ bih,   // [4H]
    const float* __restrict__ bhh,   // [4H]
    float* __restrict__ out) {

    const int b = blockIdx.x * 256 + threadIdx.x;
    const float* xrow = x + (size_t)b * TT * II;
    float* orow = out + (size_t)b * TT * HH;
    float* hN = out + (size_t)BB * TT * HH + (size_t)b * HH;
    float* cN = out + (size_t)BB * TT * HH + (size_t)BB * HH + (size_t)b * HH;

    float h[HH], c[HH];
#pragma unroll
    for (int n = 0; n < HH; n++) { h[n] = 0.f; c[n] = 0.f; }

#pragma unroll 1
    for (int t = 0; t < TT; t++) {
        // x row for this timestep: 36 fp32 = 144 B, 16B-aligned (b*2880 + t*144)
        float xr[II];
        const float4* xv = (const float4*)(xrow + t * II);
#pragma unroll
        for (int q = 0; q < II / 4; q++) {
            float4 u = xv[q];
            xr[4 * q + 0] = u.x;
            xr[4 * q + 1] = u.y;
            xr[4 * q + 2] = u.z;
            xr[4 * q + 3] = u.w;
        }

        float hn[HH];
#pragma unroll 2
        for (int n = 0; n < HH; n++) {
            float ai = bih[n] + bhh[n];
            float af = bih[n + HH] + bhh[n + HH];
            float ag = bih[n + 2 * HH] + bhh[n + 2 * HH];
            float ao = bih[n + 3 * HH] + bhh[n + 3 * HH];
            const float* wi = Wih + n * II;   // wave-uniform -> s_load
#pragma unroll
            for (int k = 0; k < II; k++) {
                float xk = xr[k];
                ai += wi[k] * xk;
                af += wi[HH * II + k] * xk;
                ag += wi[2 * HH * II + k] * xk;
                ao += wi[3 * HH * II + k] * xk;
            }
            const float* wh = Whh + n * HH;   // wave-uniform -> s_load
#pragma unroll
            for (int k = 0; k < HH; k++) {
                float hk = h[k];
                ai += wh[k] * hk;
                af += wh[HH * HH + k] * hk;
                ag += wh[2 * HH * HH + k] * hk;
                ao += wh[3 * HH * HH + k] * hk;
            }
            float it = fast_sigmoid(ai);
            float ft = fast_sigmoid(af);
            float gt = fast_tanh(ag);
            float ot = fast_sigmoid(ao);
            float cn = ft * c[n] + it * gt;
            c[n] = cn;
            hn[n] = ot * fast_tanh(cn);
        }

        // store h_t: 30 fp32 = 120 B, 8B-aligned (b*2400 + t*120) -> float2
        float2* op = (float2*)(orow + t * HH);
#pragma unroll
        for (int q = 0; q < HH / 2; q++) {
            op[q] = make_float2(hn[2 * q], hn[2 * q + 1]);
        }
#pragma unroll
        for (int n = 0; n < HH; n++) h[n] = hn[n];
    }

    float2* hp = (float2*)hN;
    float2* cp = (float2*)cN;
#pragma unroll
    for (int q = 0; q < HH / 2; q++) {
        hp[q] = make_float2(h[2 * q], h[2 * q + 1]);
        cp[q] = make_float2(c[2 * q], c[2 * q + 1]);
    }
}

extern "C" void kernel_launch(void* const* d_in, const int* in_sizes, int n_in,
                              void* d_out, int out_size, void* d_ws, size_t ws_size,
                              hipStream_t stream) {
    const float* x    = (const float*)d_in[0];
    const float* w_ih = (const float*)d_in[1];
    const float* w_hh = (const float*)d_in[2];
    const float* b_ih = (const float*)d_in[3];
    const float* b_hh = (const float*)d_in[4];
    float* out = (float*)d_out;

    hipLaunchKernelGGL(lstm_fwd, dim3(BB / 256), dim3(256), 0, stream,
                       x, w_ih, w_hh, b_ih, b_hh, out);
}